// Round 15
// baseline (234.533 us; speedup 1.0000x reference)
//
#include <hip/hip_runtime.h>

#define N_NODES 10000
#define N_EDGES 320000
#define E_TOT   (N_EDGES + N_NODES)
#define HID 256
#define NEG_SLOPE 0.2f
#define SLOTS 192   // fixed CSR slots/node; deg ~ Binom(320k,1e-4), mean 32

typedef __attribute__((ext_vector_type(8))) short short8;
typedef __attribute__((ext_vector_type(4))) float float4v;

// ---- all scratch in module-scope device globals (no d_ws dependency) ----
// g_cnt: zero at module load; re-zeroed by k_agg1's epilogue each call.
__device__ int   g_cnt[N_NODES];
__device__ int   g_csr[(size_t)N_NODES * SLOTS];
__device__ __align__(16) float g_xl[(size_t)N_NODES * HID];   // f32 (layer-3 use)
__device__ __align__(16) float g_xr[(size_t)N_NODES * HID];
__device__ __align__(16) float g_h1[(size_t)N_NODES * HID];
__device__ __align__(16) unsigned short g_xlb[(size_t)N_NODES * HID];  // bf16 xl (gather payload)
__device__ __align__(16) unsigned short g_abf[(size_t)N_NODES * 512];
__device__ __align__(16) unsigned short g_bp1b[16 * 16 * 64 * 8];  // W2l
__device__ __align__(16) unsigned short g_bp2b[16 * 16 * 64 * 8];  // W2r
__device__ __align__(16) unsigned short g_bp1c[2  * 16 * 64 * 8];  // W3l
__device__ __align__(16) unsigned short g_bp2c[2  * 16 * 64 * 8];  // W3r

#define LOG2E 1.44269504088896340736f

// ---------------- bf16 helpers (RNE) ----------------
__device__ __forceinline__ unsigned short f2bf(float f) {
    unsigned int u = __float_as_uint(f);
    unsigned int r = (u + 0x7fffu + ((u >> 16) & 1u)) >> 16;
    return (unsigned short)r;
}
__device__ __forceinline__ float bf2f(unsigned short h) {
    return __uint_as_float(((unsigned int)h) << 16);
}
__device__ __forceinline__ unsigned int splitpack(float f) {
    unsigned short hi = f2bf(f);
    unsigned short lo = f2bf(f - bf2f(hi));
    return ((unsigned int)lo << 16) | hi;   // mem halfwords: [2i]=hi, [2i+1]=lo
}

// pack one weight matrix B[K,N] into per-lane MFMA B-fragments (split-bf16).
__device__ __forceinline__ void packB(const float* __restrict__ B,
                                      unsigned short* __restrict__ Bp,
                                      int t, int nkc, int N) {
    int lane = t & 63;
    int kc   = (t >> 6) % nkc;
    int nt   = (t >> 6) / nkc;
    int n = nt * 16 + (lane & 15);
    int kbase = kc * 32 + (lane >> 4) * 8;
    #pragma unroll
    for (int j = 0; j < 8; ++j) {
        int kp = kbase + j;
        int k  = kp >> 1;
        float f = B[(size_t)k * N + n];
        unsigned short hi = f2bf(f);
        Bp[(size_t)t * 8 + j] = (kp & 1) ? f2bf(f - bf2f(hi)) : hi;
    }
}

// ===== mega launch: CSR fill | L1 dual GEMM (inline-B) | pack W2/W3 ======
// Roles are mutually independent (GEMM1's B comes straight from f32 W1,
// fill's cnt was zeroed by the previous call's agg1 / load-time init, and
// the W2/W3 packs have no consumer until later launches).
#define FILL_BLOCKS ((E_TOT + 255) / 256)            // 1290
#define GEMM1_TILES ((N_NODES + 31) / 32)            // 313
#define MEGA_G1     (FILL_BLOCKS + GEMM1_TILES)      // 1603
#define MEGA_PB     (MEGA_G1 + 64)                   // +64 blocks: pack bp1b/bp2b
#define MEGA_PC     (MEGA_PB + 8)                    // +8 blocks: pack bp1c/bp2c
__global__ __launch_bounds__(256) void k_mega(
    const int* __restrict__ ei,
    int* __restrict__ cnt, int* __restrict__ csr,
    const float4* __restrict__ A4,          // x, [N,128] f32
    const float* __restrict__ W1l, const float* __restrict__ W1r,
    const float* __restrict__ W2l, const float* __restrict__ W2r,
    const float* __restrict__ W3l, const float* __restrict__ W3r,
    unsigned short* __restrict__ C1b,       // xl out (bf16)
    float* __restrict__ C2)                 // xr out (f32)
{
    if (blockIdx.x < FILL_BLOCKS) {
        // ---- CSR slot-fill over all edges (+ appended self-loops) ----
        int e = blockIdx.x * 256 + threadIdx.x;
        if (e < E_TOT) {
            int src, dst;
            if (e < N_EDGES) { src = ei[e]; dst = ei[N_EDGES + e]; }
            else             { src = dst = e - N_EDGES; }
            int pos = atomicAdd(&cnt[dst], 1);
            if (pos < SLOTS) csr[dst * SLOTS + pos] = src;
        }
        return;
    }
    if (blockIdx.x >= MEGA_G1) {
        // ---- weight packing for layers 2 and 3 ----
        if (blockIdx.x < MEGA_PB) {
            int u = (blockIdx.x - MEGA_G1) * 256 + threadIdx.x;  // < 16384
            packB(W2l, g_bp1b, u, 16, 256);
            packB(W2r, g_bp2b, u, 16, 256);
        } else if (blockIdx.x < MEGA_PC) {
            int u = (blockIdx.x - MEGA_PB) * 256 + threadIdx.x;  // < 2048
            packB(W3l, g_bp1c, u, 16, 32);
            packB(W3r, g_bp2c, u, 16, 32);
        }
        return;
    }
    // ---- layer-1 dual GEMM: 32-row tiles, K=128; A f32 inline split; ----
    // ---- B-frags built inline from f32 W1 (L2-resident, 128 KB each) ----
    const int nkc = 8;                   // Kp = 256
    int mt   = blockIdx.x - FILL_BLOCKS;
    int lane = threadIdx.x & 63;
    int wid  = threadIdx.x >> 6;
    int quad = lane >> 4;
    int col  = lane & 15;
    int bn = lane & 15;                  // B column within nt tile
    int bk = (lane >> 4) * 4;            // B k-offset within kc tile (16 k/kc)
    int r0 = mt * 32 + col;       if (r0 >= N_NODES) r0 = N_NODES - 1;
    int r1 = mt * 32 + 16 + col;  if (r1 >= N_NODES) r1 = N_NODES - 1;
    const float4* a0 = A4 + (size_t)r0 * 32 + quad;   // K/4 = 32
    const float4* a1 = A4 + (size_t)r1 * 32 + quad;
    float4v acc[2][4][2];
    #pragma unroll
    for (int s = 0; s < 2; ++s)
        #pragma unroll
        for (int t = 0; t < 4; ++t) { acc[s][t][0] = (float4v)(0.f); acc[s][t][1] = (float4v)(0.f); }
    for (int kc = 0; kc < nkc; ++kc) {
        float4 v0 = a0[kc * 4];
        float4 v1 = a1[kc * 4];
        union { short8 s; unsigned int u[4]; } c0, c1;
        c0.u[0] = splitpack(v0.x); c0.u[1] = splitpack(v0.y);
        c0.u[2] = splitpack(v0.z); c0.u[3] = splitpack(v0.w);
        c1.u[0] = splitpack(v1.x); c1.u[1] = splitpack(v1.y);
        c1.u[2] = splitpack(v1.z); c1.u[3] = splitpack(v1.w);
        short8 A0 = c0.s, A1 = c1.s;
        int k0 = kc * 16 + bk;
        #pragma unroll
        for (int t = 0; t < 4; ++t) {
            int n = (wid * 4 + t) * 16 + bn;
            const float* w1p = W1l + (size_t)k0 * 256 + n;
            const float* w2p = W1r + (size_t)k0 * 256 + n;
            union { short8 s; unsigned int u[4]; } b1v, b2v;
            #pragma unroll
            for (int m = 0; m < 4; ++m) {
                b1v.u[m] = splitpack(w1p[(size_t)m * 256]);
                b2v.u[m] = splitpack(w2p[(size_t)m * 256]);
            }
            short8 b1 = b1v.s, b2 = b2v.s;
            acc[0][t][0] = __builtin_amdgcn_mfma_f32_16x16x32_bf16(A0, b1, acc[0][t][0], 0, 0, 0);
            acc[0][t][1] = __builtin_amdgcn_mfma_f32_16x16x32_bf16(A0, b2, acc[0][t][1], 0, 0, 0);
            acc[1][t][0] = __builtin_amdgcn_mfma_f32_16x16x32_bf16(A1, b1, acc[1][t][0], 0, 0, 0);
            acc[1][t][1] = __builtin_amdgcn_mfma_f32_16x16x32_bf16(A1, b2, acc[1][t][1], 0, 0, 0);
        }
    }
    #pragma unroll
    for (int s = 0; s < 2; ++s) {
        #pragma unroll
        for (int t = 0; t < 4; ++t) {
            int gc = (wid * 4 + t) * 16 + col;
            #pragma unroll
            for (int r = 0; r < 4; ++r) {
                int row = mt * 32 + s * 16 + quad * 4 + r;
                if (row < N_NODES) {
                    C1b[(size_t)row * 256 + gc] = f2bf(acc[s][t][0][r]);
                    C2[(size_t)row * 256 + gc]  = acc[s][t][1][r];
                }
            }
        }
    }
}

// ---------- MFMA split-bf16 dual GEMM (A pre-split): N=256 ---------------
__global__ __launch_bounds__(256) void k_mgemm2(const short8* __restrict__ Af,
                                                const short8* __restrict__ Bp1,
                                                const short8* __restrict__ Bp2,
                                                unsigned short* __restrict__ C1b,
                                                float* __restrict__ C2,
                                                int Kp, int nkc) {
    int mt   = blockIdx.x;
    int lane = threadIdx.x & 63;
    int wid  = threadIdx.x >> 6;
    int quad = lane >> 4;
    int col  = lane & 15;
    int ks   = Kp >> 3;
    int r0 = mt * 32 + col;       if (r0 >= N_NODES) r0 = N_NODES - 1;
    int r1 = mt * 32 + 16 + col;  if (r1 >= N_NODES) r1 = N_NODES - 1;
    const short8* a0 = Af + (size_t)r0 * ks + quad;
    const short8* a1 = Af + (size_t)r1 * ks + quad;
    float4v acc[2][4][2];
    #pragma unroll
    for (int s = 0; s < 2; ++s)
        #pragma unroll
        for (int t = 0; t < 4; ++t) { acc[s][t][0] = (float4v)(0.f); acc[s][t][1] = (float4v)(0.f); }
    for (int kc = 0; kc < nkc; ++kc) {
        short8 A0 = a0[kc * 4];
        short8 A1 = a1[kc * 4];
        #pragma unroll
        for (int t = 0; t < 4; ++t) {
            int nt = wid * 4 + t;
            size_t bi = ((size_t)(nt * nkc + kc)) * 64 + lane;
            short8 b1 = Bp1[bi];
            short8 b2 = Bp2[bi];
            acc[0][t][0] = __builtin_amdgcn_mfma_f32_16x16x32_bf16(A0, b1, acc[0][t][0], 0, 0, 0);
            acc[0][t][1] = __builtin_amdgcn_mfma_f32_16x16x32_bf16(A0, b2, acc[0][t][1], 0, 0, 0);
            acc[1][t][0] = __builtin_amdgcn_mfma_f32_16x16x32_bf16(A1, b1, acc[1][t][0], 0, 0, 0);
            acc[1][t][1] = __builtin_amdgcn_mfma_f32_16x16x32_bf16(A1, b2, acc[1][t][1], 0, 0, 0);
        }
    }
    #pragma unroll
    for (int s = 0; s < 2; ++s) {
        #pragma unroll
        for (int t = 0; t < 4; ++t) {
            int gc = (wid * 4 + t) * 16 + col;
            #pragma unroll
            for (int r = 0; r < 4; ++r) {
                int row = mt * 32 + s * 16 + quad * 4 + r;
                if (row < N_NODES) {
                    C1b[(size_t)row * 256 + gc] = f2bf(acc[s][t][0][r]);
                    C2[(size_t)row * 256 + gc]  = acc[s][t][1][r];
                }
            }
        }
    }
}

// ---------- MFMA dual GEMM, layer 3: N=32, Kp=512 (f32 outputs) ----------
__global__ __launch_bounds__(256) void k_mgemm32(const short8* __restrict__ Af,
                                                 const short8* __restrict__ Bp1,
                                                 const short8* __restrict__ Bp2,
                                                 float* __restrict__ C1,
                                                 float* __restrict__ C2) {
    int mt   = blockIdx.x;
    int lane = threadIdx.x & 63;
    int wid  = threadIdx.x >> 6;
    int quad = lane >> 4;
    int col  = lane & 15;
    int nt   = wid & 1;
    const short8* Bp = (wid < 2) ? Bp1 : Bp2;
    float* C = (wid < 2) ? C1 : C2;

    const short8* abase = Af + (size_t)(mt * 16 + col) * 64 + quad;  // Kp/8 = 64
    float4v acc = (float4v)(0.f);
    #pragma unroll 4
    for (int kc = 0; kc < 16; ++kc) {
        short8 a = abase[kc * 4];
        short8 b = Bp[((size_t)(nt * 16 + kc)) * 64 + lane];
        acc = __builtin_amdgcn_mfma_f32_16x16x32_bf16(a, b, acc, 0, 0, 0);
    }
    #pragma unroll
    for (int r = 0; r < 4; ++r)
        C[(size_t)(mt * 16 + quad * 4 + r) * 32 + nt * 16 + col] = acc[r];
}

// ------------- GATv2 attention + aggregation, heads=8, ch=32 -------------
// Block per node, 4 waves; wave covers full 256-ch row (float4/lane).
// Contiguous edge spans + one coalesced csr chunk-load per wave (span<=48),
// per-edge src via __shfl broadcast. leaky(t)=max(t,0.2t); att pre-scaled
// by log2e so softmax is raw exp2.
__global__ __launch_bounds__(256) void k_agg8(const unsigned short* __restrict__ xlb,
                                              const float4* __restrict__ xr4,
                                              const float4* __restrict__ att4,
                                              const float4* __restrict__ bias4,
                                              const int* __restrict__ cnt,
                                              const int* __restrict__ csr_src,
                                              const float4* __restrict__ res4,
                                              float4* __restrict__ out4,
                                              uint4* __restrict__ abf_out,
                                              int mode) {
    __shared__ float  ss[4][64];
    __shared__ float4 sacc[4][64];
    int node = blockIdx.x;
    int lane = threadIdx.x & 63;
    int wid  = threadIdx.x >> 6;
    float4 xrv = xr4[(size_t)node * 64 + lane];
    float4 av  = att4[lane];
    av.x *= LOG2E; av.y *= LOG2E; av.z *= LOG2E; av.w *= LOG2E;
    int c = cnt[node]; if (c > SLOTS) c = SLOTS;
    int start = node * SLOTS, end = start + c;
    int span = (c + 3) >> 2;             // contiguous edges per wave, <= 48
    int wbeg = start + wid * span;
    int wend = wbeg + span; if (wend > end) wend = end;
    int nloc = wend - wbeg;              // may be <= 0 for trailing waves

    int ldi = wbeg + lane;
    int idxv = csr_src[ldi < end ? ldi : (end - 1)];

    float s = 0.f;
    float4 acc = make_float4(0.f, 0.f, 0.f, 0.f);

    for (int j0 = 0; j0 < nloc; j0 += 4) {
        int srcs[4];
        ushort4 uv[4];
        #pragma unroll
        for (int j = 0; j < 4; ++j)
            srcs[j] = __shfl(idxv, j0 + j);
        #pragma unroll
        for (int j = 0; j < 4; ++j)
            uv[j] = *(const ushort4*)(xlb + (size_t)srcs[j] * 256 + 4 * lane);
        #pragma unroll
        for (int j = 0; j < 4; ++j) {
            if (j0 + j < nloc) {
                float4 xv;
                xv.x = bf2f(uv[j].x); xv.y = bf2f(uv[j].y);
                xv.z = bf2f(uv[j].z); xv.w = bf2f(uv[j].w);
                float tx = xv.x + xrv.x, ty = xv.y + xrv.y;
                float tz = xv.z + xrv.z, tw = xv.w + xrv.w;
                float w = fmaxf(tx, NEG_SLOPE * tx) * av.x
                        + fmaxf(ty, NEG_SLOPE * ty) * av.y
                        + fmaxf(tz, NEG_SLOPE * tz) * av.z
                        + fmaxf(tw, NEG_SLOPE * tw) * av.w;
                w += __shfl_xor(w, 1);
                w += __shfl_xor(w, 2);
                w += __shfl_xor(w, 4);
                float p = exp2f(w);
                s += p;
                acc.x += p * xv.x;
                acc.y += p * xv.y;
                acc.z += p * xv.z;
                acc.w += p * xv.w;
            }
        }
    }
    ss[wid][lane] = s;
    sacc[wid][lane] = acc;
    __syncthreads();
    if (wid == 0) {
        float S = ss[0][lane] + ss[1][lane] + ss[2][lane] + ss[3][lane];
        float4 A = make_float4(0.f, 0.f, 0.f, 0.f);
        #pragma unroll
        for (int w = 0; w < 4; ++w) {
            float4 a = sacc[w][lane];
            A.x += a.x; A.y += a.y; A.z += a.z; A.w += a.w;
        }
        float inv = 1.f / (S + 1e-16f);
        float4 bv = bias4[lane];
        float4 o;
        o.x = A.x * inv + bv.x; o.y = A.y * inv + bv.y;
        o.z = A.z * inv + bv.z; o.w = A.w * inv + bv.w;
        if (mode == 0) {
            o.x = fmaxf(o.x, 0.f); o.y = fmaxf(o.y, 0.f);
            o.z = fmaxf(o.z, 0.f); o.w = fmaxf(o.w, 0.f);
        } else {
            float4 r = res4[(size_t)node * 64 + lane];
            o.x += r.x; o.y += r.y; o.z += r.z; o.w += r.w;
        }
        if (out4) out4[(size_t)node * 64 + lane] = o;
        if (abf_out) {
            uint4 u;
            u.x = splitpack(o.x); u.y = splitpack(o.y);
            u.z = splitpack(o.z); u.w = splitpack(o.w);
            abf_out[(size_t)node * 64 + lane] = u;
        }
    }
}

// ------------- GATv2 attention + aggregation, heads=1, ch=32 -------------
// Epilogue re-zeros cnt[node] for the NEXT call (agg1 is the last consumer;
// module load provides the first call's zeros).
__global__ __launch_bounds__(256) void k_agg1(const float4* __restrict__ xl4,
                                              const float4* __restrict__ xr4,
                                              const float4* __restrict__ att4,
                                              const float4* __restrict__ bias4,
                                              int* __restrict__ cnt,
                                              const int* __restrict__ csr_src,
                                              float4* __restrict__ out4) {
    int node = blockIdx.x * 4 + (threadIdx.x >> 6);
    if (node >= N_NODES) return;
    int lane = threadIdx.x & 63;
    int q = lane & 7;
    int grp = lane >> 3;
    float4 xrv = xr4[(size_t)node * 8 + q];
    float4 av  = att4[q];
    av.x *= LOG2E; av.y *= LOG2E; av.z *= LOG2E; av.w *= LOG2E;
    int c = cnt[node]; if (c > SLOTS) c = SLOTS;
    int start = node * SLOTS, end = start + c;
    float s = 0.f;
    float4 acc = make_float4(0.f, 0.f, 0.f, 0.f);
    for (int i = start + grp; i < end; i += 8) {
        int src = csr_src[i];
        float4 xv = xl4[(size_t)src * 8 + q];
        float tx = xv.x + xrv.x, ty = xv.y + xrv.y;
        float tz = xv.z + xrv.z, tw = xv.w + xrv.w;
        float w = fmaxf(tx, NEG_SLOPE * tx) * av.x
                + fmaxf(ty, NEG_SLOPE * ty) * av.y
                + fmaxf(tz, NEG_SLOPE * tz) * av.z
                + fmaxf(tw, NEG_SLOPE * tw) * av.w;
        w += __shfl_xor(w, 1);
        w += __shfl_xor(w, 2);
        w += __shfl_xor(w, 4);
        float p = exp2f(w);
        s += p;
        acc.x += p * xv.x;
        acc.y += p * xv.y;
        acc.z += p * xv.z;
        acc.w += p * xv.w;
    }
    #pragma unroll
    for (int off = 8; off < 64; off <<= 1) {
        s     += __shfl_xor(s, off);
        acc.x += __shfl_xor(acc.x, off);
        acc.y += __shfl_xor(acc.y, off);
        acc.z += __shfl_xor(acc.z, off);
        acc.w += __shfl_xor(acc.w, off);
    }
    if (grp == 0) {
        float inv = 1.f / (s + 1e-16f);
        float4 bv = bias4[q];
        float4 o;
        o.x = acc.x * inv + bv.x; o.y = acc.y * inv + bv.y;
        o.z = acc.z * inv + bv.z; o.w = acc.w * inv + bv.w;
        out4[(size_t)node * 8 + q] = o;
        if (q == 0) cnt[node] = 0;     // reset for next call
    }
}

// -------------------------------- launch --------------------------------

extern "C" void kernel_launch(void* const* d_in, const int* in_sizes, int n_in,
                              void* d_out, int out_size, void* d_ws, size_t ws_size,
                              hipStream_t stream) {
    const float* x   = (const float*)d_in[0];
    const float* W1l = (const float*)d_in[1];
    const float* W1r = (const float*)d_in[2];
    const float* a1  = (const float*)d_in[3];
    const float* b1  = (const float*)d_in[4];
    const float* W2l = (const float*)d_in[5];
    const float* W2r = (const float*)d_in[6];
    const float* a2  = (const float*)d_in[7];
    const float* b2  = (const float*)d_in[8];
    const float* W3l = (const float*)d_in[9];
    const float* W3r = (const float*)d_in[10];
    const float* a3  = (const float*)d_in[11];
    const float* b3  = (const float*)d_in[12];
    const int*   ei  = (const int*)d_in[13];   // int32! harness converts int64 -> int32
    float* out = (float*)d_out;

    int *cnt, *csr;
    float *xl, *xr, *h1;
    unsigned short *xlb, *abf, *bp1b, *bp2b, *bp1c, *bp2c;
    hipGetSymbolAddress((void**)&cnt,    HIP_SYMBOL(g_cnt));
    hipGetSymbolAddress((void**)&csr,    HIP_SYMBOL(g_csr));
    hipGetSymbolAddress((void**)&xl,     HIP_SYMBOL(g_xl));
    hipGetSymbolAddress((void**)&xr,     HIP_SYMBOL(g_xr));
    hipGetSymbolAddress((void**)&h1,     HIP_SYMBOL(g_h1));
    hipGetSymbolAddress((void**)&xlb,    HIP_SYMBOL(g_xlb));
    hipGetSymbolAddress((void**)&abf,    HIP_SYMBOL(g_abf));
    hipGetSymbolAddress((void**)&bp1b,   HIP_SYMBOL(g_bp1b));
    hipGetSymbolAddress((void**)&bp2b,   HIP_SYMBOL(g_bp2b));
    hipGetSymbolAddress((void**)&bp1c,   HIP_SYMBOL(g_bp1c));
    hipGetSymbolAddress((void**)&bp2c,   HIP_SYMBOL(g_bp2c));

    // 1: mega — CSR fill + layer-1 dual GEMM (inline B) + pack W2/W3
    k_mega<<<MEGA_PC, 256, 0, stream>>>(ei, cnt, csr, (const float4*)x,
                                        W1l, W1r, W2l, W2r, W3l, W3r,
                                        xlb, xr);

    // 2: layer-1 aggregation (emits h1 f32 + abf split-bf16)
    k_agg8<<<N_NODES, 256, 0, stream>>>(xlb, (const float4*)xr,
                                        (const float4*)a1, (const float4*)b1,
                                        cnt, csr, nullptr, (float4*)h1,
                                        (uint4*)abf, 0);

    // 3: layer-2 dual GEMM (Kp=512 from abf)
    k_mgemm2<<<(N_NODES + 31) / 32, 256, 0, stream>>>((const short8*)abf,
                                                      (const short8*)bp1b, (const short8*)bp2b,
                                                      xlb, xr, 512, 16);

    // 4: layer-2 aggregation (+ residual; emits abf for L3)
    k_agg8<<<N_NODES, 256, 0, stream>>>(xlb, (const float4*)xr,
                                        (const float4*)a2, (const float4*)b2,
                                        cnt, csr, (const float4*)h1, nullptr,
                                        (uint4*)abf, 1);

    // 5: layer-3 dual GEMM (N=32)
    k_mgemm32<<<N_NODES / 16, 256, 0, stream>>>((const short8*)abf,
                                                (const short8*)bp1c, (const short8*)bp2c,
                                                xl, xr);

    // 6: heads=1 aggregation -> output (+ cnt reset for next call)
    k_agg1<<<(N_NODES + 3) / 4, 256, 0, stream>>>((const float4*)xl, (const float4*)xr,
                                                  (const float4*)a3, (const float4*)b3,
                                                  cnt, csr, (float4*)out);
}

// Round 16
// 222.268 us; speedup vs baseline: 1.0552x; 1.0552x over previous
//
#include <hip/hip_runtime.h>

#define N_NODES 10000
#define N_EDGES 320000
#define E_TOT   (N_EDGES + N_NODES)
#define HID 256
#define NEG_SLOPE 0.2f
#define SLOTS 192   // fixed CSR slots/node; deg ~ Binom(320k,1e-4), mean 32

typedef __attribute__((ext_vector_type(8))) short short8;
typedef __attribute__((ext_vector_type(4))) float float4v;

// ---- all scratch in module-scope device globals (no d_ws dependency) ----
__device__ int   g_cnt[N_NODES];
__device__ int   g_csr[(size_t)N_NODES * SLOTS];
__device__ __align__(16) float g_xl[(size_t)N_NODES * HID];   // f32 (layer-3 use)
__device__ __align__(16) float g_xr[(size_t)N_NODES * HID];
__device__ __align__(16) float g_h1[(size_t)N_NODES * HID];
__device__ __align__(16) unsigned short g_xlb[(size_t)N_NODES * HID];  // bf16 xl (gather payload)
__device__ __align__(16) unsigned short g_abf[(size_t)N_NODES * 512];
__device__ __align__(16) unsigned short g_bp1a[16 * 8  * 64 * 8];  // W1l
__device__ __align__(16) unsigned short g_bp2a[16 * 8  * 64 * 8];  // W1r
__device__ __align__(16) unsigned short g_bp1b[16 * 16 * 64 * 8];  // W2l
__device__ __align__(16) unsigned short g_bp2b[16 * 16 * 64 * 8];  // W2r
__device__ __align__(16) unsigned short g_bp1c[2  * 16 * 64 * 8];  // W3l
__device__ __align__(16) unsigned short g_bp2c[2  * 16 * 64 * 8];  // W3r

#define LOG2E 1.44269504088896340736f

// ---------------- bf16 helpers (RNE) ----------------
__device__ __forceinline__ unsigned short f2bf(float f) {
    unsigned int u = __float_as_uint(f);
    unsigned int r = (u + 0x7fffu + ((u >> 16) & 1u)) >> 16;
    return (unsigned short)r;
}
__device__ __forceinline__ float bf2f(unsigned short h) {
    return __uint_as_float(((unsigned int)h) << 16);
}
__device__ __forceinline__ unsigned int splitpack(float f) {
    unsigned short hi = f2bf(f);
    unsigned short lo = f2bf(f - bf2f(hi));
    return ((unsigned int)lo << 16) | hi;   // mem halfwords: [2i]=hi, [2i+1]=lo
}

// pack one weight matrix B[K,N] into per-lane MFMA B-fragments (split-bf16).
__device__ __forceinline__ void packB(const float* __restrict__ B,
                                      unsigned short* __restrict__ Bp,
                                      int t, int nkc, int N) {
    int lane = t & 63;
    int kc   = (t >> 6) % nkc;
    int nt   = (t >> 6) / nkc;
    int n = nt * 16 + (lane & 15);
    int kbase = kc * 32 + (lane >> 4) * 8;
    #pragma unroll
    for (int j = 0; j < 8; ++j) {
        int kp = kbase + j;
        int k  = kp >> 1;
        float f = B[(size_t)k * N + n];
        unsigned short hi = f2bf(f);
        Bp[(size_t)t * 8 + j] = (kp & 1) ? f2bf(f - bf2f(hi)) : hi;
    }
}

// ---- prep: pack all six weight matrices + zero the slot counters ----
__global__ __launch_bounds__(256) void k_prep(const float* __restrict__ W1l,
                                              const float* __restrict__ W1r,
                                              const float* __restrict__ W2l,
                                              const float* __restrict__ W2r,
                                              const float* __restrict__ W3l,
                                              const float* __restrict__ W3r,
                                              int* __restrict__ cnt) {
    const int S0 = 16 * 8 * 64;    // 8192
    const int S1 = 16 * 16 * 64;   // 16384
    const int S2 = 2 * 16 * 64;    // 2048
    int t = blockIdx.x * blockDim.x + threadIdx.x;
    if (t < S0) {
        packB(W1l, g_bp1a, t, 8, 256);
        packB(W1r, g_bp2a, t, 8, 256);
    } else if (t < S0 + S1) {
        int u = t - S0;
        packB(W2l, g_bp1b, u, 16, 256);
        packB(W2r, g_bp2b, u, 16, 256);
    } else if (t < S0 + S1 + S2) {
        int u = t - S0 - S1;
        packB(W3l, g_bp1c, u, 16, 32);
        packB(W3r, g_bp2c, u, 16, 32);
    } else {
        int u = t - S0 - S1 - S2;
        if (u < N_NODES) cnt[u] = 0;
    }
}

// ==== fill CSR slots (blocks [0,FB)) + layer-1 dual GEMM (rest) ==========
#define FILL_BLOCKS ((E_TOT + 255) / 256)   // 1290
__global__ __launch_bounds__(256) void k_fill_gemm1(
    const int* __restrict__ ei,
    int* __restrict__ cnt, int* __restrict__ csr,
    const float4* __restrict__ A4,          // x, [N,128] f32
    const short8* __restrict__ Bp1, const short8* __restrict__ Bp2,
    unsigned short* __restrict__ C1b,       // xl out (bf16)
    float* __restrict__ C2)                 // xr out (f32)
{
    if (blockIdx.x < FILL_BLOCKS) {
        int e = blockIdx.x * 256 + threadIdx.x;
        if (e < E_TOT) {
            int src, dst;
            if (e < N_EDGES) { src = ei[e]; dst = ei[N_EDGES + e]; }
            else             { src = dst = e - N_EDGES; }
            int pos = atomicAdd(&cnt[dst], 1);
            if (pos < SLOTS) csr[dst * SLOTS + pos] = src;
        }
        return;
    }
    // ---- layer-1 dual GEMM: 32-row tiles, K=128 f32 inline split ----
    const int nkc = 8;                   // Kp = 256
    int mt   = blockIdx.x - FILL_BLOCKS;
    int lane = threadIdx.x & 63;
    int wid  = threadIdx.x >> 6;
    int quad = lane >> 4;
    int col  = lane & 15;
    int r0 = mt * 32 + col;       if (r0 >= N_NODES) r0 = N_NODES - 1;
    int r1 = mt * 32 + 16 + col;  if (r1 >= N_NODES) r1 = N_NODES - 1;
    const float4* a0 = A4 + (size_t)r0 * 32 + quad;   // K/4 = 32
    const float4* a1 = A4 + (size_t)r1 * 32 + quad;
    float4v acc[2][4][2];
    #pragma unroll
    for (int s = 0; s < 2; ++s)
        #pragma unroll
        for (int t = 0; t < 4; ++t) { acc[s][t][0] = (float4v)(0.f); acc[s][t][1] = (float4v)(0.f); }
    for (int kc = 0; kc < nkc; ++kc) {
        float4 v0 = a0[kc * 4];
        float4 v1 = a1[kc * 4];
        union { short8 s; unsigned int u[4]; } c0, c1;
        c0.u[0] = splitpack(v0.x); c0.u[1] = splitpack(v0.y);
        c0.u[2] = splitpack(v0.z); c0.u[3] = splitpack(v0.w);
        c1.u[0] = splitpack(v1.x); c1.u[1] = splitpack(v1.y);
        c1.u[2] = splitpack(v1.z); c1.u[3] = splitpack(v1.w);
        short8 A0 = c0.s, A1 = c1.s;
        #pragma unroll
        for (int t = 0; t < 4; ++t) {
            int nt = wid * 4 + t;
            size_t bi = ((size_t)(nt * nkc + kc)) * 64 + lane;
            short8 b1 = Bp1[bi];
            short8 b2 = Bp2[bi];
            acc[0][t][0] = __builtin_amdgcn_mfma_f32_16x16x32_bf16(A0, b1, acc[0][t][0], 0, 0, 0);
            acc[0][t][1] = __builtin_amdgcn_mfma_f32_16x16x32_bf16(A0, b2, acc[0][t][1], 0, 0, 0);
            acc[1][t][0] = __builtin_amdgcn_mfma_f32_16x16x32_bf16(A1, b1, acc[1][t][0], 0, 0, 0);
            acc[1][t][1] = __builtin_amdgcn_mfma_f32_16x16x32_bf16(A1, b2, acc[1][t][1], 0, 0, 0);
        }
    }
    #pragma unroll
    for (int s = 0; s < 2; ++s) {
        #pragma unroll
        for (int t = 0; t < 4; ++t) {
            int gc = (wid * 4 + t) * 16 + col;
            #pragma unroll
            for (int r = 0; r < 4; ++r) {
                int row = mt * 32 + s * 16 + quad * 4 + r;
                if (row < N_NODES) {
                    C1b[(size_t)row * 256 + gc] = f2bf(acc[s][t][0][r]);
                    C2[(size_t)row * 256 + gc]  = acc[s][t][1][r];
                }
            }
        }
    }
}

// ---------- MFMA split-bf16 dual GEMM (A pre-split): N=256 ---------------
__global__ __launch_bounds__(256) void k_mgemm2(const short8* __restrict__ Af,
                                                const short8* __restrict__ Bp1,
                                                const short8* __restrict__ Bp2,
                                                unsigned short* __restrict__ C1b,
                                                float* __restrict__ C2,
                                                int Kp, int nkc) {
    int mt   = blockIdx.x;
    int lane = threadIdx.x & 63;
    int wid  = threadIdx.x >> 6;
    int quad = lane >> 4;
    int col  = lane & 15;
    int ks   = Kp >> 3;
    int r0 = mt * 32 + col;       if (r0 >= N_NODES) r0 = N_NODES - 1;
    int r1 = mt * 32 + 16 + col;  if (r1 >= N_NODES) r1 = N_NODES - 1;
    const short8* a0 = Af + (size_t)r0 * ks + quad;
    const short8* a1 = Af + (size_t)r1 * ks + quad;
    float4v acc[2][4][2];
    #pragma unroll
    for (int s = 0; s < 2; ++s)
        #pragma unroll
        for (int t = 0; t < 4; ++t) { acc[s][t][0] = (float4v)(0.f); acc[s][t][1] = (float4v)(0.f); }
    for (int kc = 0; kc < nkc; ++kc) {
        short8 A0 = a0[kc * 4];
        short8 A1 = a1[kc * 4];
        #pragma unroll
        for (int t = 0; t < 4; ++t) {
            int nt = wid * 4 + t;
            size_t bi = ((size_t)(nt * nkc + kc)) * 64 + lane;
            short8 b1 = Bp1[bi];
            short8 b2 = Bp2[bi];
            acc[0][t][0] = __builtin_amdgcn_mfma_f32_16x16x32_bf16(A0, b1, acc[0][t][0], 0, 0, 0);
            acc[0][t][1] = __builtin_amdgcn_mfma_f32_16x16x32_bf16(A0, b2, acc[0][t][1], 0, 0, 0);
            acc[1][t][0] = __builtin_amdgcn_mfma_f32_16x16x32_bf16(A1, b1, acc[1][t][0], 0, 0, 0);
            acc[1][t][1] = __builtin_amdgcn_mfma_f32_16x16x32_bf16(A1, b2, acc[1][t][1], 0, 0, 0);
        }
    }
    #pragma unroll
    for (int s = 0; s < 2; ++s) {
        #pragma unroll
        for (int t = 0; t < 4; ++t) {
            int gc = (wid * 4 + t) * 16 + col;
            #pragma unroll
            for (int r = 0; r < 4; ++r) {
                int row = mt * 32 + s * 16 + quad * 4 + r;
                if (row < N_NODES) {
                    C1b[(size_t)row * 256 + gc] = f2bf(acc[s][t][0][r]);
                    C2[(size_t)row * 256 + gc]  = acc[s][t][1][r];
                }
            }
        }
    }
}

// ---------- MFMA dual GEMM, layer 3: N=32, Kp=512 (f32 outputs) ----------
__global__ __launch_bounds__(256) void k_mgemm32(const short8* __restrict__ Af,
                                                 const short8* __restrict__ Bp1,
                                                 const short8* __restrict__ Bp2,
                                                 float* __restrict__ C1,
                                                 float* __restrict__ C2) {
    int mt   = blockIdx.x;
    int lane = threadIdx.x & 63;
    int wid  = threadIdx.x >> 6;
    int quad = lane >> 4;
    int col  = lane & 15;
    int nt   = wid & 1;
    const short8* Bp = (wid < 2) ? Bp1 : Bp2;
    float* C = (wid < 2) ? C1 : C2;

    const short8* abase = Af + (size_t)(mt * 16 + col) * 64 + quad;  // Kp/8 = 64
    float4v acc = (float4v)(0.f);
    #pragma unroll 4
    for (int kc = 0; kc < 16; ++kc) {
        short8 a = abase[kc * 4];
        short8 b = Bp[((size_t)(nt * 16 + kc)) * 64 + lane];
        acc = __builtin_amdgcn_mfma_f32_16x16x32_bf16(a, b, acc, 0, 0, 0);
    }
    #pragma unroll
    for (int r = 0; r < 4; ++r)
        C[(size_t)(mt * 16 + quad * 4 + r) * 32 + nt * 16 + col] = acc[r];
}

// ------------- GATv2 attention + aggregation, heads=8, ch=32 -------------
// Block per node, 4 waves; wave covers full 256-ch row (float4/lane).
// Contiguous edge spans + one coalesced csr chunk-load per wave (span<=48),
// per-edge src via __shfl broadcast. leaky(t)=max(t,0.2t); att pre-scaled
// by log2e so softmax is raw exp2.
__global__ __launch_bounds__(256) void k_agg8(const unsigned short* __restrict__ xlb,
                                              const float4* __restrict__ xr4,
                                              const float4* __restrict__ att4,
                                              const float4* __restrict__ bias4,
                                              const int* __restrict__ cnt,
                                              const int* __restrict__ csr_src,
                                              const float4* __restrict__ res4,
                                              float4* __restrict__ out4,
                                              uint4* __restrict__ abf_out,
                                              int mode) {
    __shared__ float  ss[4][64];
    __shared__ float4 sacc[4][64];
    int node = blockIdx.x;
    int lane = threadIdx.x & 63;
    int wid  = threadIdx.x >> 6;
    float4 xrv = xr4[(size_t)node * 64 + lane];
    float4 av  = att4[lane];
    av.x *= LOG2E; av.y *= LOG2E; av.z *= LOG2E; av.w *= LOG2E;
    int c = cnt[node]; if (c > SLOTS) c = SLOTS;
    int start = node * SLOTS, end = start + c;
    int span = (c + 3) >> 2;             // contiguous edges per wave, <= 48
    int wbeg = start + wid * span;
    int wend = wbeg + span; if (wend > end) wend = end;
    int nloc = wend - wbeg;              // may be <= 0 for trailing waves

    int ldi = wbeg + lane;
    int idxv = csr_src[ldi < end ? ldi : (end - 1)];

    float s = 0.f;
    float4 acc = make_float4(0.f, 0.f, 0.f, 0.f);

    for (int j0 = 0; j0 < nloc; j0 += 4) {
        int srcs[4];
        ushort4 uv[4];
        #pragma unroll
        for (int j = 0; j < 4; ++j)
            srcs[j] = __shfl(idxv, j0 + j);
        #pragma unroll
        for (int j = 0; j < 4; ++j)
            uv[j] = *(const ushort4*)(xlb + (size_t)srcs[j] * 256 + 4 * lane);
        #pragma unroll
        for (int j = 0; j < 4; ++j) {
            if (j0 + j < nloc) {
                float4 xv;
                xv.x = bf2f(uv[j].x); xv.y = bf2f(uv[j].y);
                xv.z = bf2f(uv[j].z); xv.w = bf2f(uv[j].w);
                float tx = xv.x + xrv.x, ty = xv.y + xrv.y;
                float tz = xv.z + xrv.z, tw = xv.w + xrv.w;
                float w = fmaxf(tx, NEG_SLOPE * tx) * av.x
                        + fmaxf(ty, NEG_SLOPE * ty) * av.y
                        + fmaxf(tz, NEG_SLOPE * tz) * av.z
                        + fmaxf(tw, NEG_SLOPE * tw) * av.w;
                w += __shfl_xor(w, 1);
                w += __shfl_xor(w, 2);
                w += __shfl_xor(w, 4);
                float p = exp2f(w);
                s += p;
                acc.x += p * xv.x;
                acc.y += p * xv.y;
                acc.z += p * xv.z;
                acc.w += p * xv.w;
            }
        }
    }
    ss[wid][lane] = s;
    sacc[wid][lane] = acc;
    __syncthreads();
    if (wid == 0) {
        float S = ss[0][lane] + ss[1][lane] + ss[2][lane] + ss[3][lane];
        float4 A = make_float4(0.f, 0.f, 0.f, 0.f);
        #pragma unroll
        for (int w = 0; w < 4; ++w) {
            float4 a = sacc[w][lane];
            A.x += a.x; A.y += a.y; A.z += a.z; A.w += a.w;
        }
        float inv = 1.f / (S + 1e-16f);
        float4 bv = bias4[lane];
        float4 o;
        o.x = A.x * inv + bv.x; o.y = A.y * inv + bv.y;
        o.z = A.z * inv + bv.z; o.w = A.w * inv + bv.w;
        if (mode == 0) {
            o.x = fmaxf(o.x, 0.f); o.y = fmaxf(o.y, 0.f);
            o.z = fmaxf(o.z, 0.f); o.w = fmaxf(o.w, 0.f);
        } else {
            float4 r = res4[(size_t)node * 64 + lane];
            o.x += r.x; o.y += r.y; o.z += r.z; o.w += r.w;
        }
        if (out4) out4[(size_t)node * 64 + lane] = o;
        if (abf_out) {
            uint4 u;
            u.x = splitpack(o.x); u.y = splitpack(o.y);
            u.z = splitpack(o.z); u.w = splitpack(o.w);
            abf_out[(size_t)node * 64 + lane] = u;
        }
    }
}

// ------------- GATv2 attention + aggregation, heads=1, ch=32 -------------
__global__ __launch_bounds__(256) void k_agg1(const float4* __restrict__ xl4,
                                              const float4* __restrict__ xr4,
                                              const float4* __restrict__ att4,
                                              const float4* __restrict__ bias4,
                                              const int* __restrict__ cnt,
                                              const int* __restrict__ csr_src,
                                              float4* __restrict__ out4) {
    int node = blockIdx.x * 4 + (threadIdx.x >> 6);
    if (node >= N_NODES) return;
    int lane = threadIdx.x & 63;
    int q = lane & 7;
    int grp = lane >> 3;
    float4 xrv = xr4[(size_t)node * 8 + q];
    float4 av  = att4[q];
    av.x *= LOG2E; av.y *= LOG2E; av.z *= LOG2E; av.w *= LOG2E;
    int c = cnt[node]; if (c > SLOTS) c = SLOTS;
    int start = node * SLOTS, end = start + c;
    float s = 0.f;
    float4 acc = make_float4(0.f, 0.f, 0.f, 0.f);
    for (int i = start + grp; i < end; i += 8) {
        int src = csr_src[i];
        float4 xv = xl4[(size_t)src * 8 + q];
        float tx = xv.x + xrv.x, ty = xv.y + xrv.y;
        float tz = xv.z + xrv.z, tw = xv.w + xrv.w;
        float w = fmaxf(tx, NEG_SLOPE * tx) * av.x
                + fmaxf(ty, NEG_SLOPE * ty) * av.y
                + fmaxf(tz, NEG_SLOPE * tz) * av.z
                + fmaxf(tw, NEG_SLOPE * tw) * av.w;
        w += __shfl_xor(w, 1);
        w += __shfl_xor(w, 2);
        w += __shfl_xor(w, 4);
        float p = exp2f(w);
        s += p;
        acc.x += p * xv.x;
        acc.y += p * xv.y;
        acc.z += p * xv.z;
        acc.w += p * xv.w;
    }
    #pragma unroll
    for (int off = 8; off < 64; off <<= 1) {
        s     += __shfl_xor(s, off);
        acc.x += __shfl_xor(acc.x, off);
        acc.y += __shfl_xor(acc.y, off);
        acc.z += __shfl_xor(acc.z, off);
        acc.w += __shfl_xor(acc.w, off);
    }
    if (grp == 0) {
        float inv = 1.f / (s + 1e-16f);
        float4 bv = bias4[q];
        float4 o;
        o.x = acc.x * inv + bv.x; o.y = acc.y * inv + bv.y;
        o.z = acc.z * inv + bv.z; o.w = acc.w * inv + bv.w;
        out4[(size_t)node * 8 + q] = o;
    }
}

// -------------------------------- launch --------------------------------

extern "C" void kernel_launch(void* const* d_in, const int* in_sizes, int n_in,
                              void* d_out, int out_size, void* d_ws, size_t ws_size,
                              hipStream_t stream) {
    const float* x   = (const float*)d_in[0];
    const float* W1l = (const float*)d_in[1];
    const float* W1r = (const float*)d_in[2];
    const float* a1  = (const float*)d_in[3];
    const float* b1  = (const float*)d_in[4];
    const float* W2l = (const float*)d_in[5];
    const float* W2r = (const float*)d_in[6];
    const float* a2  = (const float*)d_in[7];
    const float* b2  = (const float*)d_in[8];
    const float* W3l = (const float*)d_in[9];
    const float* W3r = (const float*)d_in[10];
    const float* a3  = (const float*)d_in[11];
    const float* b3  = (const float*)d_in[12];
    const int*   ei  = (const int*)d_in[13];   // int32! harness converts int64 -> int32
    float* out = (float*)d_out;

    int *cnt, *csr;
    float *xl, *xr, *h1;
    unsigned short *xlb, *abf, *bp1a, *bp2a, *bp1b, *bp2b, *bp1c, *bp2c;
    hipGetSymbolAddress((void**)&cnt,    HIP_SYMBOL(g_cnt));
    hipGetSymbolAddress((void**)&csr,    HIP_SYMBOL(g_csr));
    hipGetSymbolAddress((void**)&xl,     HIP_SYMBOL(g_xl));
    hipGetSymbolAddress((void**)&xr,     HIP_SYMBOL(g_xr));
    hipGetSymbolAddress((void**)&h1,     HIP_SYMBOL(g_h1));
    hipGetSymbolAddress((void**)&xlb,    HIP_SYMBOL(g_xlb));
    hipGetSymbolAddress((void**)&abf,    HIP_SYMBOL(g_abf));
    hipGetSymbolAddress((void**)&bp1a,   HIP_SYMBOL(g_bp1a));
    hipGetSymbolAddress((void**)&bp2a,   HIP_SYMBOL(g_bp2a));
    hipGetSymbolAddress((void**)&bp1b,   HIP_SYMBOL(g_bp1b));
    hipGetSymbolAddress((void**)&bp2b,   HIP_SYMBOL(g_bp2b));
    hipGetSymbolAddress((void**)&bp1c,   HIP_SYMBOL(g_bp1c));
    hipGetSymbolAddress((void**)&bp2c,   HIP_SYMBOL(g_bp2c));

    // 1: pack 6 weight mats + zero slot counters
    k_prep<<<144, 256, 0, stream>>>(W1l, W1r, W2l, W2r, W3l, W3r, cnt);

    // 2: CSR slot-fill + layer-1 dual GEMM (independent roles, one launch)
    k_fill_gemm1<<<FILL_BLOCKS + (N_NODES + 31) / 32, 256, 0, stream>>>(
        ei, cnt, csr, (const float4*)x,
        (const short8*)bp1a, (const short8*)bp2a, xlb, xr);

    // 3: layer-1 aggregation (emits h1 f32 + abf split-bf16)
    k_agg8<<<N_NODES, 256, 0, stream>>>(xlb, (const float4*)xr,
                                        (const float4*)a1, (const float4*)b1,
                                        cnt, csr, nullptr, (float4*)h1,
                                        (uint4*)abf, 0);

    // 4: layer-2 dual GEMM (Kp=512 from abf)
    k_mgemm2<<<(N_NODES + 31) / 32, 256, 0, stream>>>((const short8*)abf,
                                                      (const short8*)bp1b, (const short8*)bp2b,
                                                      xlb, xr, 512, 16);

    // 5: layer-2 aggregation (+ residual; emits abf for L3)
    k_agg8<<<N_NODES, 256, 0, stream>>>(xlb, (const float4*)xr,
                                        (const float4*)a2, (const float4*)b2,
                                        cnt, csr, (const float4*)h1, nullptr,
                                        (uint4*)abf, 1);

    // 6: layer-3 dual GEMM (N=32)
    k_mgemm32<<<N_NODES / 16, 256, 0, stream>>>((const short8*)abf,
                                                (const short8*)bp1c, (const short8*)bp2c,
                                                xl, xr);

    // 7: heads=1 aggregation -> output
    k_agg1<<<(N_NODES + 3) / 4, 256, 0, stream>>>((const float4*)xl, (const float4*)xr,
                                                  (const float4*)a3, (const float4*)b3,
                                                  cnt, csr, (float4*)out);
}